// Round 10
// baseline (836.839 us; speedup 1.0000x reference)
//
#include <hip/hip_runtime.h>
#include <math.h>

#define NB 16
#define NS 4096
#define NH 768
#define NC 64      // chunks per batch
#define CHUNK 64   // rows per chunk
#define NBLK (NB * NC)

static constexpr float kEps = 1e-9f;

// ---------------------------------------------------------------------------
// Fused single-pass kernel, decoupled chunk aggregates.
// Grid = 1024 blocks (b,c) = exactly 4 blocks/CU x 256 CU -> fully co-resident
// (LDS 15.6KB, VGPR capped at 128 by __launch_bounds__(256,4)), so the
// flag-wait cannot deadlock regardless of dispatch order.
//
// Phase A: each of 4 waves owns 16 rows; dot(x,W) via 12 FMAs + butterfly;
//          aj = exp(dot+bias); per-wave numerator acc in regs -> LDS.
// Publish: chunk aggregate (768 floats + a-sum) -> global, threadfence,
//          release flag.
// Lookback: wait on the c predecessor flags, then all 256 threads sum
//          predecessors' aggregates from L2 -> chunk-exclusive offsets in LDS.
// Phase C: each wave replays its own 16 rows (x re-read is L2/L3-warm),
//          out = run_num/run_den with exclusive semantics, 1-row prefetch.
// ---------------------------------------------------------------------------
__global__ __launch_bounds__(256, 4) void la_fused(
    const float* __restrict__ x, const float* __restrict__ Wp,
    const float* __restrict__ bp,
    float* __restrict__ agg,          // [NBLK][NH]
    float* __restrict__ agg_a,        // [NBLK]
    unsigned int* __restrict__ flag,  // [NBLK], pre-zeroed
    float* __restrict__ out)
{
  const int blk  = blockIdx.x;
  const int b    = blk >> 6;   // / NC
  const int c    = blk & 63;   // % NC
  const int t    = threadIdx.x;
  const int w    = t >> 6;
  const int lane = t & 63;
  const float bias = bp[0];

  __shared__ float lacc[4][NH];   // per-wave numerator aggregates
  __shared__ float la[CHUNK];     // aj per row of this chunk
  __shared__ float lsum[4];       // per-wave a-sums
  __shared__ float cex[NH];       // chunk-exclusive numerator offset
  __shared__ float cex_a;         // chunk-exclusive denominator offset

  // ---- Phase A ----
  const float4* W4 = reinterpret_cast<const float4*>(Wp);
  const float4 w0 = W4[lane];
  const float4 w1 = W4[64 + lane];
  const float4 w2 = W4[128 + lane];

  float4 acc0 = {0.f,0.f,0.f,0.f};
  float4 acc1 = {0.f,0.f,0.f,0.f};
  float4 acc2 = {0.f,0.f,0.f,0.f};
  float wsum = 0.f;
  float areg = 0.f;

  const int row0 = c * CHUNK + w * 16;
  const float* xb = x + (size_t)(b * NS + row0) * NH;

  #pragma unroll 2
  for (int r = 0; r < 16; ++r) {
    const float4* X4 = reinterpret_cast<const float4*>(xb + (size_t)r * NH);
    const float4 x0 = X4[lane];
    const float4 x1 = X4[64 + lane];
    const float4 x2 = X4[128 + lane];
    float dot = x0.x*w0.x + x0.y*w0.y + x0.z*w0.z + x0.w*w0.w
              + x1.x*w1.x + x1.y*w1.y + x1.z*w1.z + x1.w*w1.w
              + x2.x*w2.x + x2.y*w2.y + x2.z*w2.z + x2.w*w2.w;
    #pragma unroll
    for (int off = 1; off < 64; off <<= 1) dot += __shfl_xor(dot, off);
    const float aj = __expf(dot + bias);
    if (lane == r) areg = aj;
    wsum += aj;
    acc0.x += aj*x0.x; acc0.y += aj*x0.y; acc0.z += aj*x0.z; acc0.w += aj*x0.w;
    acc1.x += aj*x1.x; acc1.y += aj*x1.y; acc1.z += aj*x1.z; acc1.w += aj*x1.w;
    acc2.x += aj*x2.x; acc2.y += aj*x2.y; acc2.z += aj*x2.z; acc2.w += aj*x2.w;
  }
  if (lane < 16) la[w * 16 + lane] = areg;
  {
    float4* l4 = reinterpret_cast<float4*>(lacc[w]);
    l4[lane]       = acc0;
    l4[64 + lane]  = acc1;
    l4[128 + lane] = acc2;
  }
  if (lane == 0) lsum[w] = wsum;
  __syncthreads();

  // ---- Publish chunk aggregate ----
  {
    float* ag = agg + (size_t)blk * NH;
    #pragma unroll
    for (int k = 0; k < 3; ++k) {
      const int h = t + k * 256;
      ag[h] = lacc[0][h] + lacc[1][h] + lacc[2][h] + lacc[3][h];
    }
    if (t == 0) agg_a[blk] = lsum[0] + lsum[1] + lsum[2] + lsum[3];
  }
  __threadfence();            // make payload agent-visible
  __syncthreads();            // all payload stores done before flag
  if (t == 0)
    __hip_atomic_store(&flag[blk], 1u, __ATOMIC_RELEASE, __HIP_MEMORY_SCOPE_AGENT);

  // ---- Lookback: wait for the c predecessors, then sum aggregates ----
  if (t < c) {
    while (__hip_atomic_load(&flag[b * NC + t], __ATOMIC_ACQUIRE,
                             __HIP_MEMORY_SCOPE_AGENT) == 0u) {
      __builtin_amdgcn_s_sleep(1);
    }
  }
  __syncthreads();
  __threadfence();            // ensure subsequent payload loads are fresh

  {
    float e0 = 0.f, e1 = 0.f, e2 = 0.f;
    for (int cc = 0; cc < c; ++cc) {
      const float* ap = agg + (size_t)(b * NC + cc) * NH;
      e0 += ap[t];
      e1 += ap[t + 256];
      e2 += ap[t + 512];
    }
    cex[t]       = e0;
    cex[t + 256] = e1;
    cex[t + 512] = e2;
  }
  if (w == 0) {
    float av = (lane < c) ? agg_a[b * NC + lane] : 0.f;
    #pragma unroll
    for (int off = 1; off < 64; off <<= 1) av += __shfl_xor(av, off);
    if (lane == 0) cex_a = av;
  }
  __syncthreads();

  // ---- Phase C: replay own rows ----
  float4 s0, s1, s2;
  {
    const float4* cx4 = reinterpret_cast<const float4*>(cex);
    s0 = cx4[lane]; s1 = cx4[64 + lane]; s2 = cx4[128 + lane];
    for (int w2 = 0; w2 < w; ++w2) {
      const float4* l4c = reinterpret_cast<const float4*>(lacc[w2]);
      const float4 a0 = l4c[lane], a1 = l4c[64 + lane], a2 = l4c[128 + lane];
      s0.x += a0.x; s0.y += a0.y; s0.z += a0.z; s0.w += a0.w;
      s1.x += a1.x; s1.y += a1.y; s1.z += a1.z; s1.w += a1.w;
      s2.x += a2.x; s2.y += a2.y; s2.z += a2.z; s2.w += a2.w;
    }
  }
  float dena = cex_a;
  for (int w2 = 0; w2 < w; ++w2) dena += lsum[w2];

  float* ob = out + (size_t)(b * NS + row0) * NH;
  const float4* Xp = reinterpret_cast<const float4*>(xb);
  float4 p0 = Xp[lane], p1 = Xp[64 + lane], p2 = Xp[128 + lane];

  for (int r = 0; r < 16; ++r) {
    float4 n0, n1, n2;
    if (r + 1 < 16) {
      const float4* Xn = reinterpret_cast<const float4*>(xb + (size_t)(r + 1) * NH);
      n0 = Xn[lane]; n1 = Xn[64 + lane]; n2 = Xn[128 + lane];
    }
    const float aj  = la[w * 16 + r];
    const float inv = __builtin_amdgcn_rcpf(dena + kEps);
    float4* O4 = reinterpret_cast<float4*>(ob + (size_t)r * NH);
    float4 o0, o1, o2;
    o0.x = s0.x*inv; o0.y = s0.y*inv; o0.z = s0.z*inv; o0.w = s0.w*inv;
    o1.x = s1.x*inv; o1.y = s1.y*inv; o1.z = s1.z*inv; o1.w = s1.w*inv;
    o2.x = s2.x*inv; o2.y = s2.y*inv; o2.z = s2.z*inv; o2.w = s2.w*inv;
    O4[lane]       = o0;
    O4[64 + lane]  = o1;
    O4[128 + lane] = o2;
    s0.x += aj*p0.x; s0.y += aj*p0.y; s0.z += aj*p0.z; s0.w += aj*p0.w;
    s1.x += aj*p1.x; s1.y += aj*p1.y; s1.z += aj*p1.z; s1.w += aj*p1.w;
    s2.x += aj*p2.x; s2.y += aj*p2.y; s2.z += aj*p2.z; s2.w += aj*p2.w;
    dena += aj;
    if (r + 1 < 16) { p0 = n0; p1 = n1; p2 = n2; }
  }
}

// ---------------------------------------------------------------------------
extern "C" void kernel_launch(void* const* d_in, const int* in_sizes, int n_in,
                              void* d_out, int out_size, void* d_ws, size_t ws_size,
                              hipStream_t stream) {
  const float* x  = (const float*)d_in[0];
  const float* Wp = (const float*)d_in[1];
  const float* bp = (const float*)d_in[2];
  float* out = (float*)d_out;

  char* ws = (char*)d_ws;
  float*        agg   = (float*)(ws);                        // 1024*768*4 = 3145728 B
  float*        agg_a = (float*)(ws + 3145728);              // 1024*4     = 4096 B
  unsigned int* flag  = (unsigned int*)(ws + 3145728 + 4096);// 1024*4     = 4096 B

  // ws is poisoned to 0xAA before every timed launch -> zero the flags.
  hipMemsetAsync(flag, 0, NBLK * sizeof(unsigned int), stream);

  la_fused<<<NBLK, 256, 0, stream>>>(x, Wp, bp, agg, agg_a, flag, out);
}

// Round 17
// 390.723 us; speedup vs baseline: 2.1418x; 2.1418x over previous
//
#include <hip/hip_runtime.h>
#include <math.h>

#define NB 16
#define NS 4096
#define NH 768
#define NC 64      // chunks per batch
#define CHUNK 64   // rows per chunk
#define NBLK (NB * NC)

static constexpr float kEps = 1e-9f;

// ---------------------------------------------------------------------------
// k1: per (b,c) block, 4 waves x 16 rows. GEMV dot + exp + per-wave numerator
// aggregates in registers -> LDS. Publishes:
//   a[b,s]                    per-row attention weights
//   ptot[blk][768]            chunk numerator total
//   wpre[blk][3][768]         within-chunk per-wave EXCLUSIVE prefix (w=1..3)
//   atot[blk], apre[blk][4]   denominator total + within-chunk wave prefix
// No fences: the k1->k2 kernel boundary is the (single, amortized) fence.
// ---------------------------------------------------------------------------
__global__ __launch_bounds__(256) void la_k1(
    const float* __restrict__ x, const float* __restrict__ Wp,
    const float* __restrict__ bp,
    float* __restrict__ a, float* __restrict__ ptot,
    float* __restrict__ wpre, float* __restrict__ atot,
    float* __restrict__ apre)
{
  const int blk  = blockIdx.x;
  const int b    = blk >> 6;
  const int c    = blk & 63;
  const int t    = threadIdx.x;
  const int w    = t >> 6;
  const int lane = t & 63;
  const float bias = bp[0];

  __shared__ float lacc[4][NH];
  __shared__ float lsum[4];

  const float4* W4 = reinterpret_cast<const float4*>(Wp);
  const float4 w0 = W4[lane];
  const float4 w1 = W4[64 + lane];
  const float4 w2 = W4[128 + lane];

  float4 acc0 = {0.f,0.f,0.f,0.f};
  float4 acc1 = {0.f,0.f,0.f,0.f};
  float4 acc2 = {0.f,0.f,0.f,0.f};
  float wsum = 0.f;
  float areg = 0.f;

  const int row0 = c * CHUNK + w * 16;
  const float* xb = x + (size_t)(b * NS + row0) * NH;

  #pragma unroll 2
  for (int r = 0; r < 16; ++r) {
    const float4* X4 = reinterpret_cast<const float4*>(xb + (size_t)r * NH);
    const float4 x0 = X4[lane];
    const float4 x1 = X4[64 + lane];
    const float4 x2 = X4[128 + lane];
    float dot = x0.x*w0.x + x0.y*w0.y + x0.z*w0.z + x0.w*w0.w
              + x1.x*w1.x + x1.y*w1.y + x1.z*w1.z + x1.w*w1.w
              + x2.x*w2.x + x2.y*w2.y + x2.z*w2.z + x2.w*w2.w;
    #pragma unroll
    for (int off = 1; off < 64; off <<= 1) dot += __shfl_xor(dot, off);
    const float aj = __expf(dot + bias);
    if (lane == r) areg = aj;
    wsum += aj;
    acc0.x += aj*x0.x; acc0.y += aj*x0.y; acc0.z += aj*x0.z; acc0.w += aj*x0.w;
    acc1.x += aj*x1.x; acc1.y += aj*x1.y; acc1.z += aj*x1.z; acc1.w += aj*x1.w;
    acc2.x += aj*x2.x; acc2.y += aj*x2.y; acc2.z += aj*x2.z; acc2.w += aj*x2.w;
  }
  if (lane < 16) a[(size_t)b * NS + row0 + lane] = areg;
  {
    float4* l4 = reinterpret_cast<float4*>(lacc[w]);
    l4[lane]       = acc0;
    l4[64 + lane]  = acc1;
    l4[128 + lane] = acc2;
  }
  if (lane == 0) lsum[w] = wsum;
  __syncthreads();

  {
    float* pt = ptot + (size_t)blk * NH;
    float* wp = wpre + (size_t)blk * 3 * NH;
    #pragma unroll
    for (int k = 0; k < 3; ++k) {
      const int h = t + k * 256;
      const float p0   = lacc[0][h];
      const float p01  = p0  + lacc[1][h];
      const float p012 = p01 + lacc[2][h];
      wp[h]            = p0;     // exclusive prefix for wave 1
      wp[NH + h]       = p01;    // for wave 2
      wp[2*NH + h]     = p012;   // for wave 3
      pt[h]            = p012 + lacc[3][h];
    }
  }
  if (t == 0) {
    const float s0 = lsum[0], s1 = lsum[1], s2 = lsum[2], s3 = lsum[3];
    atot[blk] = s0 + s1 + s2 + s3;
    float* ap = apre + blk * 4;
    ap[0] = 0.f; ap[1] = s0; ap[2] = s0 + s1; ap[3] = s0 + s1 + s2;
  }
}

// ---------------------------------------------------------------------------
// k2: per (b,c) block, 4 waves x 16 rows. Flat lookback over predecessor
// chunk totals (plain coalesced loads, LLC-resident), per-wave denominator
// butterfly, then phase-C replay with running exclusive num/den.
// ---------------------------------------------------------------------------
__global__ __launch_bounds__(256) void la_k2(
    const float* __restrict__ x, const float* __restrict__ a,
    const float* __restrict__ ptot, const float* __restrict__ wpre,
    const float* __restrict__ atot, const float* __restrict__ apre,
    float* __restrict__ out)
{
  const int blk  = blockIdx.x;
  const int b    = blk >> 6;
  const int c    = blk & 63;
  const int t    = threadIdx.x;
  const int w    = t >> 6;
  const int lane = t & 63;

  __shared__ float cex[NH];
  __shared__ float ldsa[CHUNK];

  if (t < CHUNK) ldsa[t] = a[(size_t)b * NS + c * CHUNK + t];

  // chunk-exclusive numerator offsets (columns t, t+256, t+512)
  {
    float e0 = 0.f, e1 = 0.f, e2 = 0.f;
    for (int cc = 0; cc < c; ++cc) {
      const float* ap = ptot + (size_t)(b * NC + cc) * NH;
      e0 += ap[t];
      e1 += ap[t + 256];
      e2 += ap[t + 512];
    }
    cex[t]       = e0;
    cex[t + 256] = e1;
    cex[t + 512] = e2;
  }
  // denominator offset: every wave computes it (butterfly over 64 lanes)
  float av = (lane < c) ? atot[b * NC + lane] : 0.f;
  #pragma unroll
  for (int off = 1; off < 64; off <<= 1) av += __shfl_xor(av, off);
  float dena = av + apre[blk * 4 + w];
  __syncthreads();

  // phase C: replay own 16 rows
  float4 s0, s1, s2;
  {
    const float4* cx4 = reinterpret_cast<const float4*>(cex);
    s0 = cx4[lane]; s1 = cx4[64 + lane]; s2 = cx4[128 + lane];
    if (w > 0) {
      const float4* wp4 = reinterpret_cast<const float4*>(
          wpre + ((size_t)blk * 3 + (w - 1)) * NH);
      const float4 a0 = wp4[lane], a1 = wp4[64 + lane], a2 = wp4[128 + lane];
      s0.x += a0.x; s0.y += a0.y; s0.z += a0.z; s0.w += a0.w;
      s1.x += a1.x; s1.y += a1.y; s1.z += a1.z; s1.w += a1.w;
      s2.x += a2.x; s2.y += a2.y; s2.z += a2.z; s2.w += a2.w;
    }
  }

  const int row0 = c * CHUNK + w * 16;
  const float* xb = x + (size_t)(b * NS + row0) * NH;
  float*       ob = out + (size_t)(b * NS + row0) * NH;

  const float4* Xp = reinterpret_cast<const float4*>(xb);
  float4 p0 = Xp[lane], p1 = Xp[64 + lane], p2 = Xp[128 + lane];

  for (int r = 0; r < 16; ++r) {
    float4 n0, n1, n2;
    if (r + 1 < 16) {
      const float4* Xn = reinterpret_cast<const float4*>(xb + (size_t)(r + 1) * NH);
      n0 = Xn[lane]; n1 = Xn[64 + lane]; n2 = Xn[128 + lane];
    }
    const float aj  = ldsa[w * 16 + r];
    const float inv = __builtin_amdgcn_rcpf(dena + kEps);
    float4* O4 = reinterpret_cast<float4*>(ob + (size_t)r * NH);
    float4 o0, o1, o2;
    o0.x = s0.x*inv; o0.y = s0.y*inv; o0.z = s0.z*inv; o0.w = s0.w*inv;
    o1.x = s1.x*inv; o1.y = s1.y*inv; o1.z = s1.z*inv; o1.w = s1.w*inv;
    o2.x = s2.x*inv; o2.y = s2.y*inv; o2.z = s2.z*inv; o2.w = s2.w*inv;
    O4[lane]       = o0;
    O4[64 + lane]  = o1;
    O4[128 + lane] = o2;
    s0.x += aj*p0.x; s0.y += aj*p0.y; s0.z += aj*p0.z; s0.w += aj*p0.w;
    s1.x += aj*p1.x; s1.y += aj*p1.y; s1.z += aj*p1.z; s1.w += aj*p1.w;
    s2.x += aj*p2.x; s2.y += aj*p2.y; s2.z += aj*p2.z; s2.w += aj*p2.w;
    dena += aj;
    if (r + 1 < 16) { p0 = n0; p1 = n1; p2 = n2; }
  }
}

// ---------------------------------------------------------------------------
extern "C" void kernel_launch(void* const* d_in, const int* in_sizes, int n_in,
                              void* d_out, int out_size, void* d_ws, size_t ws_size,
                              hipStream_t stream) {
  const float* x  = (const float*)d_in[0];
  const float* Wp = (const float*)d_in[1];
  const float* bp = (const float*)d_in[2];
  float* out = (float*)d_out;

  char* ws = (char*)d_ws;
  float* a    = (float*)(ws);                    //  262144 B
  float* ptot = (float*)(ws + 262144);           // 3145728 B
  float* wpre = (float*)(ws + 3407872);          // 9437184 B
  float* atot = (float*)(ws + 12845056);         //    4096 B
  float* apre = (float*)(ws + 12849152);         //   16384 B

  la_k1<<<NBLK, 256, 0, stream>>>(x, Wp, bp, a, ptot, wpre, atot, apre);
  la_k2<<<NBLK, 256, 0, stream>>>(x, a, ptot, wpre, atot, apre, out);
}